// Round 9
// baseline (120.071 us; speedup 1.0000x reference)
//
#include <hip/hip_runtime.h>
#include <math.h>

#define NQ 12
#define NL 4
#define NC 10
#define NB 512
#define BN_EPS 1e-5f

typedef float v2f __attribute__((ext_vector_type(2)));

// Packed complex 2x2 butterfly. Constants pre-paired:
// c0={m0,m0} c1={-m1,m1} c2={m2,m2} c3={-m3,m3} (row 0), c4..c7 row 1.
__device__ __forceinline__ void bfly(v2f& A, v2f& B,
    v2f c0, v2f c1, v2f c2, v2f c3, v2f c4, v2f c5, v2f c6, v2f c7)
{
    const v2f As = A.yx, Bs = B.yx;
    const v2f An = __builtin_elementwise_fma(c0, A,
                   __builtin_elementwise_fma(c1, As,
                   __builtin_elementwise_fma(c2, B, c3 * Bs)));
    const v2f Bn = __builtin_elementwise_fma(c4, A,
                   __builtin_elementwise_fma(c5, As,
                   __builtin_elementwise_fma(c6, B, c7 * Bs)));
    A = An; B = Bn;
}

// Round-12: r0's proven vqc (best measured, ~37us) byte-identical in the
// circuit portion, with BatchNorm FUSED via last-block pattern (counter in
// d_ws, zeroed by a 4-byte hipMemsetAsync before launch; writers
// threadfence+device-scope atomicAdd; last block re-fences and runs BN on
// the 20KB L2-resident probs matrix with bn_kernel's exact arithmetic).
// Rationale: rounds 1-8 falsified every vqc-side structural lever (phase
// count, occupancy, single-wave, cross-lane gates) -- all >= r0. The only
// remaining controllable cost is the second kernel launch (~4-6us).
__global__ __launch_bounds__(256) void vqc_kernel(
    const float* __restrict__ x, const float* __restrict__ w,
    const float* __restrict__ bias, const float* __restrict__ gamma,
    const float* __restrict__ beta, unsigned* __restrict__ ctr,
    float* __restrict__ probs)
{
    __shared__ v2f buf[2][4096];                  // 2 x 32 KB staging
    __shared__ __align__(16) float gm[48][16];    // 48 gates x 8 paired consts
    __shared__ float red[4*NC];
    __shared__ float bnS[4][NC], bnSS[4][NC], bnstat[2][NC];
    __shared__ unsigned lastflag;

    const int b = blockIdx.x;
    const int t = threadIdx.x;

    // ---- one-time: all 48 fused (Rot * RY) matrices, pre-paired/negated ----
    if (t < 48) {
        const int l = t / NQ, q = t % NQ;
        const float xq = 0.5f * x[b*NQ + q];
        const float cx = cosf(xq), sx = sinf(xq);
        const int wi = (l*NQ + q)*3;
        const float phi = w[wi], tht = w[wi+1], om = w[wi+2];
        const float ct = cosf(0.5f*tht), st = sinf(0.5f*tht);
        const float aa = 0.5f*(phi + om), dd = 0.5f*(phi - om);
        const float ca = cosf(aa), sa = sinf(aa);
        const float cd = cosf(dd), sd = sinf(dd);
        const float u00r =  ca*ct, u00i = -sa*ct;
        const float u01r = -cd*st, u01i = -sd*st;
        const float u10r =  cd*st, u10i = -sd*st;
        const float u11r =  ca*ct, u11i =  sa*ct;
        const float m00r = u00r*cx + u01r*sx, m00i = u00i*cx + u01i*sx;
        const float m01r = u01r*cx - u00r*sx, m01i = u01i*cx - u00i*sx;
        const float m10r = u10r*cx + u11r*sx, m10i = u10i*cx + u11i*sx;
        const float m11r = u11r*cx - u10r*sx, m11i = u11i*cx - u10i*sx;
        float* gp = gm[t];
        gp[0]  =  m00r; gp[1]  = m00r;
        gp[2]  = -m00i; gp[3]  = m00i;
        gp[4]  =  m01r; gp[5]  = m01r;
        gp[6]  = -m01i; gp[7]  = m01i;
        gp[8]  =  m10r; gp[9]  = m10r;
        gp[10] = -m10i; gp[11] = m10i;
        gp[12] =  m11r; gp[13] = m11r;
        gp[14] = -m11i; gp[15] = m11i;
    }
    __syncthreads();

    // ---- registers: stage-A layout, global i = (r<<8)|t ----
    v2f a[16];
    #pragma unroll
    for (int r = 0; r < 16; ++r) a[r] = (v2f){0.f, 0.f};
    if (t == 0) a[0].x = 1.f;

    const int tl = t & 15, th4 = t >> 4;
    const int phit = t ^ th4;                       // phi(t)
    const int vAB = (th4 << 8) | (tl ^ (th4 * 17)); // A->B write base
    const int wBC = (tl << 8) | ((th4 ^ tl) * 17);  // B->C write base

    // ---- C->A' (CNOT ring) per-thread constants ----
    const unsigned b0_ = t & 1u, b1_ = (t>>1)&1u, b2_ = (t>>2)&1u, b3_ = (t>>3)&1u,
                   b4_ = (t>>4)&1u, b5_ = (t>>5)&1u, b6_ = (t>>6)&1u, b7_ = (t>>7)&1u;
    const unsigned P7 = b7_, P6 = P7^b6_, P5 = P6^b5_, P4 = P5^b4_,
                   P3 = P4^b3_, P2 = P3^b2_, P1 = P2^b1_, T = P1^b0_;  // Pk = parity(t>>k)
    const unsigned base_j = ((T ^ b7_) << 11) | (P6 << 10) | (P5 << 9) | (P4 << 8)
                          | (P3 << 7) | (P2 << 6) | (P1 << 5) | (T << 4)
                          | (T ? 0xFu : 0u);
    const unsigned rA = (base_j >> 8) & 15u;
    const unsigned tA = base_j & 255u;
    const unsigned baseCA = (rA << 8) | ((tA ^ (tA >> 4)) ^ (rA * 17u));

    // Gates in ascending bit order (1,2,4,8): first gate after a transition
    // needs only a[0],a[1]. Bit (1<<g) -> gm[base+3-g].
    #define STAGE(base) \
        _Pragma("unroll") \
        for (int g = 0; g < 4; ++g) { \
            const v2f* cp = (const v2f*)gm[(base) + 3 - g]; \
            const v2f c0=cp[0],c1=cp[1],c2=cp[2],c3=cp[3], \
                      c4=cp[4],c5=cp[5],c6=cp[6],c7=cp[7]; \
            const int bit = 1 << g; \
            _Pragma("unroll") \
            for (int r0 = 0; r0 < 16; ++r0) \
                if (!(r0 & bit)) bfly(a[r0], a[r0|bit], c0,c1,c2,c3,c4,c5,c6,c7); \
        }

    int pb = 0;  // staging buffer parity (folds under full unroll)
    #pragma unroll
    for (int l = 0; l < NL; ++l) {
        // ---- stage 0: qubits 0..3 ----
        STAGE(l*12)
        // ---- transition A->B (single barrier, double-buffered) ----
        {
            v2f* bp = buf[pb]; pb ^= 1;
            #pragma unroll
            for (int r = 0; r < 16; ++r) bp[vAB ^ (r*17)] = a[r];
            __syncthreads();
            #pragma unroll
            for (int r = 0; r < 16; ++r) a[r] = bp[(r<<8) | (phit ^ (r*17))];
        }

        // ---- stage 1: qubits 4..7 ----
        STAGE(l*12 + 4)
        // ---- transition B->C ----
        {
            v2f* bp = buf[pb]; pb ^= 1;
            #pragma unroll
            for (int r = 0; r < 16; ++r) bp[wBC ^ r] = a[r];
            __syncthreads();
            #pragma unroll
            for (int r = 0; r < 16; ++r) a[r] = bp[(r<<8) | (phit ^ (r*17))];
        }

        // ---- stage 2: qubits 8..11 ----
        STAGE(l*12 + 8)
        if (l < NL-1) {
            // ---- transition C->A' with ring-CNOT permutation fused ----
            v2f* bp = buf[pb]; pb ^= 1;
            #pragma unroll
            for (int r = 0; r < 16; ++r) {
                const unsigned k3 = (r>>3)&1u;
                const unsigned k2 = k3 ^ ((r>>2)&1u);
                const unsigned k1 = k2 ^ ((r>>1)&1u);
                const unsigned k0 = k1 ^ (r&1u);           // = par(r)
                const unsigned K  = (k3<<3)|(k2<<2)|(k1<<1)|k0;
                const unsigned d  = K ^ (k0 * 0x888u);     // compile-time per r
                bp[baseCA ^ d] = a[r];
            }
            __syncthreads();
            #pragma unroll
            for (int r = 0; r < 16; ++r) a[r] = bp[(r<<8) | (phit ^ (r*17))];
        }
    }

    // ---- readout: signs are bits of j = M(i), i = (t<<4)|r ----
    const float S0 = (T ^ b7_) ? -1.f : 1.f;  // j_11 base (flip by par(r))
    const float S1 = P6 ? -1.f : 1.f;         // j_10
    const float S2 = P5 ? -1.f : 1.f;         // j_9
    const float S3 = P4 ? -1.f : 1.f;         // j_8
    const float S4 = P3 ? -1.f : 1.f;         // j_7
    const float S5 = P2 ? -1.f : 1.f;         // j_6
    const float S6 = P1 ? -1.f : 1.f;         // j_5
    const float S7 = T  ? -1.f : 1.f;         // j_4
    const float S8 = T  ? -1.f : 1.f;         // j_3 base (flip by r3)
    const float S9 = T  ? -1.f : 1.f;         // j_2 base (flip by r3^r2)

    float acc[NC];
    #pragma unroll
    for (int c = 0; c < NC; ++c) acc[c] = 0.f;
    #pragma unroll
    for (int r = 0; r < 16; ++r) {
        const float p = a[r].x*a[r].x + a[r].y*a[r].y;
        const int r3 = (r>>3)&1, r2 = (r>>2)&1, r1 = (r>>1)&1, r0b = r&1;
        const int par = r3 ^ r2 ^ r1 ^ r0b;
        acc[0] += (par        ? -S0 : S0) * p;
        acc[1] += S1 * p;
        acc[2] += S2 * p;
        acc[3] += S3 * p;
        acc[4] += S4 * p;
        acc[5] += S5 * p;
        acc[6] += S6 * p;
        acc[7] += S7 * p;
        acc[8] += (r3         ? -S8 : S8) * p;
        acc[9] += ((r3 ^ r2)  ? -S9 : S9) * p;
    }
    #pragma unroll
    for (int off = 32; off >= 1; off >>= 1) {
        #pragma unroll
        for (int c = 0; c < NC; ++c)
            acc[c] += __shfl_down(acc[c], off, 64);
    }
    const int wave = t >> 6, lane = t & 63;
    if (lane == 0) {
        #pragma unroll
        for (int c = 0; c < NC; ++c) red[wave*NC + c] = acc[c];
    }
    __syncthreads();
    if (t == 0) {
        float ez[NC];
        float mx = -1e30f;
        #pragma unroll
        for (int c = 0; c < NC; ++c) {
            ez[c] = red[c] + red[NC + c] + red[2*NC + c] + red[3*NC + c] + bias[c];
            mx = fmaxf(mx, ez[c]);
        }
        float sum = 0.f;
        #pragma unroll
        for (int c = 0; c < NC; ++c) { ez[c] = expf(ez[c] - mx); sum += ez[c]; }
        const float inv = 1.f / sum;
        #pragma unroll
        for (int c = 0; c < NC; ++c) probs[b*NC + c] = ez[c] * inv;
    }

    // ==== fused BatchNorm: last-block pattern ====
    __threadfence();                         // make probs visible device-wide
    if (t == 0) lastflag = (atomicAdd(ctr, 1u) == (unsigned)(NB - 1));
    __syncthreads();
    if (!lastflag) return;
    __threadfence();                         // acquire: others' probs visible

    // BN over probs[512][10] by this one block (20 KB, L2-resident).
    float v0[NC], v1[NC], ps[NC], pss[NC];
    const float* r0p = probs + t*NC;
    const float* r1p = probs + (t + 256)*NC;
    #pragma unroll
    for (int c = 0; c < NC; ++c) {
        v0[c] = r0p[c]; v1[c] = r1p[c];
        ps[c]  = v0[c] + v1[c];
        pss[c] = v0[c]*v0[c] + v1[c]*v1[c];
    }
    #pragma unroll
    for (int off = 32; off >= 1; off >>= 1) {
        #pragma unroll
        for (int c = 0; c < NC; ++c) {
            ps[c]  += __shfl_down(ps[c],  off, 64);
            pss[c] += __shfl_down(pss[c], off, 64);
        }
    }
    if (lane == 0) {
        #pragma unroll
        for (int c = 0; c < NC; ++c) { bnS[wave][c] = ps[c]; bnSS[wave][c] = pss[c]; }
    }
    __syncthreads();
    if (t < NC) {
        const float S  = bnS[0][t] + bnS[1][t] + bnS[2][t] + bnS[3][t];
        const float SS = bnSS[0][t] + bnSS[1][t] + bnSS[2][t] + bnSS[3][t];
        const float mu  = S * (1.f/512.f);
        const float var = SS * (1.f/512.f) - mu*mu;
        bnstat[0][t] = mu;
        bnstat[1][t] = 1.f / sqrtf(var + BN_EPS);
    }
    __syncthreads();
    float* w0p = probs + t*NC;
    float* w1p = probs + (t + 256)*NC;
    #pragma unroll
    for (int c = 0; c < NC; ++c) {
        const float mu = bnstat[0][c], inv = bnstat[1][c];
        const float g = gamma[c], bt = beta[c];
        w0p[c] = (v0[c] - mu) * inv * g + bt;
        w1p[c] = (v1[c] - mu) * inv * g + bt;
    }
}

extern "C" void kernel_launch(void* const* d_in, const int* in_sizes, int n_in,
                              void* d_out, int out_size, void* d_ws, size_t ws_size,
                              hipStream_t stream) {
    const float* x     = (const float*)d_in[0];   // (512, 12)
    const float* w     = (const float*)d_in[1];   // (4, 12, 3)
    const float* bias  = (const float*)d_in[2];   // (10,)
    const float* gamma = (const float*)d_in[3];   // (10,)
    const float* beta  = (const float*)d_in[4];   // (10,)
    float* out = (float*)d_out;                   // (512, 10) float32

    // zero the completion counter (d_ws is poisoned by the harness)
    hipMemsetAsync(d_ws, 0, sizeof(unsigned), stream);
    vqc_kernel<<<NB, 256, 0, stream>>>(x, w, bias, gamma, beta,
                                       (unsigned*)d_ws, out);
}

// Round 10
// 93.065 us; speedup vs baseline: 1.2902x; 1.2902x over previous
//
#include <hip/hip_runtime.h>
#include <math.h>

#define NQ 12
#define NL 4
#define NC 10
#define NB 512
#define BN_EPS 1e-5f

typedef float v2f __attribute__((ext_vector_type(2)));

// Packed complex 2x2 butterfly. Constants pre-paired:
// c0={m0,m0} c1={-m1,m1} c2={m2,m2} c3={-m3,m3} (row 0), c4..c7 row 1.
__device__ __forceinline__ void bfly(v2f& A, v2f& B,
    v2f c0, v2f c1, v2f c2, v2f c3, v2f c4, v2f c5, v2f c6, v2f c7)
{
    const v2f As = A.yx, Bs = B.yx;
    const v2f An = __builtin_elementwise_fma(c0, A,
                   __builtin_elementwise_fma(c1, As,
                   __builtin_elementwise_fma(c2, B, c3 * Bs)));
    const v2f Bn = __builtin_elementwise_fma(c4, A,
                   __builtin_elementwise_fma(c5, As,
                   __builtin_elementwise_fma(c6, B, c7 * Bs)));
    A = An; B = Bn;
}

// Round-13: fused BN, fence-minimized. Round-9's fusion regressed vqc
// 37->64.5us with VALUBusy DOWN (26->18%): stall, not work. Cause: the
// release __threadfence() ran in ALL 256 threads (4 waves/block -> 2048
// L2-writeback ops chip-wide, on an L2 left dirty by the 256MB harness
// fill). But only t==0 writes probs, so only t0 needs release ordering.
// Fix: fence+atomicAdd by t0 only (1 fence-wave/block, draining only t0's
// own stores); acquire fence only inside the single last block.
// Circuit portion remains byte-identical to round-0 (best measured ~37us).
__global__ __launch_bounds__(256) void vqc_kernel(
    const float* __restrict__ x, const float* __restrict__ w,
    const float* __restrict__ bias, const float* __restrict__ gamma,
    const float* __restrict__ beta, unsigned* __restrict__ ctr,
    float* __restrict__ probs)
{
    __shared__ v2f buf[2][4096];                  // 2 x 32 KB staging
    __shared__ __align__(16) float gm[48][16];    // 48 gates x 8 paired consts
    __shared__ float red[4*NC];
    __shared__ float bnS[4][NC], bnSS[4][NC], bnstat[2][NC];
    __shared__ unsigned lastflag;

    const int b = blockIdx.x;
    const int t = threadIdx.x;

    // ---- one-time: all 48 fused (Rot * RY) matrices, pre-paired/negated ----
    if (t < 48) {
        const int l = t / NQ, q = t % NQ;
        const float xq = 0.5f * x[b*NQ + q];
        const float cx = cosf(xq), sx = sinf(xq);
        const int wi = (l*NQ + q)*3;
        const float phi = w[wi], tht = w[wi+1], om = w[wi+2];
        const float ct = cosf(0.5f*tht), st = sinf(0.5f*tht);
        const float aa = 0.5f*(phi + om), dd = 0.5f*(phi - om);
        const float ca = cosf(aa), sa = sinf(aa);
        const float cd = cosf(dd), sd = sinf(dd);
        const float u00r =  ca*ct, u00i = -sa*ct;
        const float u01r = -cd*st, u01i = -sd*st;
        const float u10r =  cd*st, u10i = -sd*st;
        const float u11r =  ca*ct, u11i =  sa*ct;
        const float m00r = u00r*cx + u01r*sx, m00i = u00i*cx + u01i*sx;
        const float m01r = u01r*cx - u00r*sx, m01i = u01i*cx - u00i*sx;
        const float m10r = u10r*cx + u11r*sx, m10i = u10i*cx + u11i*sx;
        const float m11r = u11r*cx - u10r*sx, m11i = u11i*cx - u10i*sx;
        float* gp = gm[t];
        gp[0]  =  m00r; gp[1]  = m00r;
        gp[2]  = -m00i; gp[3]  = m00i;
        gp[4]  =  m01r; gp[5]  = m01r;
        gp[6]  = -m01i; gp[7]  = m01i;
        gp[8]  =  m10r; gp[9]  = m10r;
        gp[10] = -m10i; gp[11] = m10i;
        gp[12] =  m11r; gp[13] = m11r;
        gp[14] = -m11i; gp[15] = m11i;
    }
    __syncthreads();

    // ---- registers: stage-A layout, global i = (r<<8)|t ----
    v2f a[16];
    #pragma unroll
    for (int r = 0; r < 16; ++r) a[r] = (v2f){0.f, 0.f};
    if (t == 0) a[0].x = 1.f;

    const int tl = t & 15, th4 = t >> 4;
    const int phit = t ^ th4;                       // phi(t)
    const int vAB = (th4 << 8) | (tl ^ (th4 * 17)); // A->B write base
    const int wBC = (tl << 8) | ((th4 ^ tl) * 17);  // B->C write base

    // ---- C->A' (CNOT ring) per-thread constants ----
    const unsigned b0_ = t & 1u, b1_ = (t>>1)&1u, b2_ = (t>>2)&1u, b3_ = (t>>3)&1u,
                   b4_ = (t>>4)&1u, b5_ = (t>>5)&1u, b6_ = (t>>6)&1u, b7_ = (t>>7)&1u;
    const unsigned P7 = b7_, P6 = P7^b6_, P5 = P6^b5_, P4 = P5^b4_,
                   P3 = P4^b3_, P2 = P3^b2_, P1 = P2^b1_, T = P1^b0_;  // Pk = parity(t>>k)
    const unsigned base_j = ((T ^ b7_) << 11) | (P6 << 10) | (P5 << 9) | (P4 << 8)
                          | (P3 << 7) | (P2 << 6) | (P1 << 5) | (T << 4)
                          | (T ? 0xFu : 0u);
    const unsigned rA = (base_j >> 8) & 15u;
    const unsigned tA = base_j & 255u;
    const unsigned baseCA = (rA << 8) | ((tA ^ (tA >> 4)) ^ (rA * 17u));

    // Gates in ascending bit order (1,2,4,8): first gate after a transition
    // needs only a[0],a[1]. Bit (1<<g) -> gm[base+3-g].
    #define STAGE(base) \
        _Pragma("unroll") \
        for (int g = 0; g < 4; ++g) { \
            const v2f* cp = (const v2f*)gm[(base) + 3 - g]; \
            const v2f c0=cp[0],c1=cp[1],c2=cp[2],c3=cp[3], \
                      c4=cp[4],c5=cp[5],c6=cp[6],c7=cp[7]; \
            const int bit = 1 << g; \
            _Pragma("unroll") \
            for (int r0 = 0; r0 < 16; ++r0) \
                if (!(r0 & bit)) bfly(a[r0], a[r0|bit], c0,c1,c2,c3,c4,c5,c6,c7); \
        }

    int pb = 0;  // staging buffer parity (folds under full unroll)
    #pragma unroll
    for (int l = 0; l < NL; ++l) {
        // ---- stage 0: qubits 0..3 ----
        STAGE(l*12)
        // ---- transition A->B (single barrier, double-buffered) ----
        {
            v2f* bp = buf[pb]; pb ^= 1;
            #pragma unroll
            for (int r = 0; r < 16; ++r) bp[vAB ^ (r*17)] = a[r];
            __syncthreads();
            #pragma unroll
            for (int r = 0; r < 16; ++r) a[r] = bp[(r<<8) | (phit ^ (r*17))];
        }

        // ---- stage 1: qubits 4..7 ----
        STAGE(l*12 + 4)
        // ---- transition B->C ----
        {
            v2f* bp = buf[pb]; pb ^= 1;
            #pragma unroll
            for (int r = 0; r < 16; ++r) bp[wBC ^ r] = a[r];
            __syncthreads();
            #pragma unroll
            for (int r = 0; r < 16; ++r) a[r] = bp[(r<<8) | (phit ^ (r*17))];
        }

        // ---- stage 2: qubits 8..11 ----
        STAGE(l*12 + 8)
        if (l < NL-1) {
            // ---- transition C->A' with ring-CNOT permutation fused ----
            v2f* bp = buf[pb]; pb ^= 1;
            #pragma unroll
            for (int r = 0; r < 16; ++r) {
                const unsigned k3 = (r>>3)&1u;
                const unsigned k2 = k3 ^ ((r>>2)&1u);
                const unsigned k1 = k2 ^ ((r>>1)&1u);
                const unsigned k0 = k1 ^ (r&1u);           // = par(r)
                const unsigned K  = (k3<<3)|(k2<<2)|(k1<<1)|k0;
                const unsigned d  = K ^ (k0 * 0x888u);     // compile-time per r
                bp[baseCA ^ d] = a[r];
            }
            __syncthreads();
            #pragma unroll
            for (int r = 0; r < 16; ++r) a[r] = bp[(r<<8) | (phit ^ (r*17))];
        }
    }

    // ---- readout: signs are bits of j = M(i), i = (t<<4)|r ----
    const float S0 = (T ^ b7_) ? -1.f : 1.f;  // j_11 base (flip by par(r))
    const float S1 = P6 ? -1.f : 1.f;         // j_10
    const float S2 = P5 ? -1.f : 1.f;         // j_9
    const float S3 = P4 ? -1.f : 1.f;         // j_8
    const float S4 = P3 ? -1.f : 1.f;         // j_7
    const float S5 = P2 ? -1.f : 1.f;         // j_6
    const float S6 = P1 ? -1.f : 1.f;         // j_5
    const float S7 = T  ? -1.f : 1.f;         // j_4
    const float S8 = T  ? -1.f : 1.f;         // j_3 base (flip by r3)
    const float S9 = T  ? -1.f : 1.f;         // j_2 base (flip by r3^r2)

    float acc[NC];
    #pragma unroll
    for (int c = 0; c < NC; ++c) acc[c] = 0.f;
    #pragma unroll
    for (int r = 0; r < 16; ++r) {
        const float p = a[r].x*a[r].x + a[r].y*a[r].y;
        const int r3 = (r>>3)&1, r2 = (r>>2)&1, r1 = (r>>1)&1, r0b = r&1;
        const int par = r3 ^ r2 ^ r1 ^ r0b;
        acc[0] += (par        ? -S0 : S0) * p;
        acc[1] += S1 * p;
        acc[2] += S2 * p;
        acc[3] += S3 * p;
        acc[4] += S4 * p;
        acc[5] += S5 * p;
        acc[6] += S6 * p;
        acc[7] += S7 * p;
        acc[8] += (r3         ? -S8 : S8) * p;
        acc[9] += ((r3 ^ r2)  ? -S9 : S9) * p;
    }
    #pragma unroll
    for (int off = 32; off >= 1; off >>= 1) {
        #pragma unroll
        for (int c = 0; c < NC; ++c)
            acc[c] += __shfl_down(acc[c], off, 64);
    }
    const int wave = t >> 6, lane = t & 63;
    if (lane == 0) {
        #pragma unroll
        for (int c = 0; c < NC; ++c) red[wave*NC + c] = acc[c];
    }
    __syncthreads();
    if (t == 0) {
        float ez[NC];
        float mx = -1e30f;
        #pragma unroll
        for (int c = 0; c < NC; ++c) {
            ez[c] = red[c] + red[NC + c] + red[2*NC + c] + red[3*NC + c] + bias[c];
            mx = fmaxf(mx, ez[c]);
        }
        float sum = 0.f;
        #pragma unroll
        for (int c = 0; c < NC; ++c) { ez[c] = expf(ez[c] - mx); sum += ez[c]; }
        const float inv = 1.f / sum;
        #pragma unroll
        for (int c = 0; c < NC; ++c) probs[b*NC + c] = ez[c] * inv;
    }

    // ==== fused BatchNorm: last-block pattern, fence-minimized ====
    // Only t0 wrote probs -> only t0 needs release ordering.
    if (t == 0) {
        __threadfence();                     // release t0's probs stores
        lastflag = (atomicAdd(ctr, 1u) == (unsigned)(NB - 1));
    }
    __syncthreads();
    if (!lastflag) return;
    __threadfence();                         // acquire (one block only, cheap)

    // BN over probs[512][10] by this one block (20 KB, L2-resident).
    float v0[NC], v1[NC], ps[NC], pss[NC];
    const float* r0p = probs + t*NC;
    const float* r1p = probs + (t + 256)*NC;
    #pragma unroll
    for (int c = 0; c < NC; ++c) {
        v0[c] = r0p[c]; v1[c] = r1p[c];
        ps[c]  = v0[c] + v1[c];
        pss[c] = v0[c]*v0[c] + v1[c]*v1[c];
    }
    #pragma unroll
    for (int off = 32; off >= 1; off >>= 1) {
        #pragma unroll
        for (int c = 0; c < NC; ++c) {
            ps[c]  += __shfl_down(ps[c],  off, 64);
            pss[c] += __shfl_down(pss[c], off, 64);
        }
    }
    if (lane == 0) {
        #pragma unroll
        for (int c = 0; c < NC; ++c) { bnS[wave][c] = ps[c]; bnSS[wave][c] = pss[c]; }
    }
    __syncthreads();
    if (t < NC) {
        const float S  = bnS[0][t] + bnS[1][t] + bnS[2][t] + bnS[3][t];
        const float SS = bnSS[0][t] + bnSS[1][t] + bnSS[2][t] + bnSS[3][t];
        const float mu  = S * (1.f/512.f);
        const float var = SS * (1.f/512.f) - mu*mu;
        bnstat[0][t] = mu;
        bnstat[1][t] = 1.f / sqrtf(var + BN_EPS);
    }
    __syncthreads();
    float* w0p = probs + t*NC;
    float* w1p = probs + (t + 256)*NC;
    #pragma unroll
    for (int c = 0; c < NC; ++c) {
        const float mu = bnstat[0][c], inv = bnstat[1][c];
        const float g = gamma[c], bt = beta[c];
        w0p[c] = (v0[c] - mu) * inv * g + bt;
        w1p[c] = (v1[c] - mu) * inv * g + bt;
    }
}

extern "C" void kernel_launch(void* const* d_in, const int* in_sizes, int n_in,
                              void* d_out, int out_size, void* d_ws, size_t ws_size,
                              hipStream_t stream) {
    const float* x     = (const float*)d_in[0];   // (512, 12)
    const float* w     = (const float*)d_in[1];   // (4, 12, 3)
    const float* bias  = (const float*)d_in[2];   // (10,)
    const float* gamma = (const float*)d_in[3];   // (10,)
    const float* beta  = (const float*)d_in[4];   // (10,)
    float* out = (float*)d_out;                   // (512, 10) float32

    // zero the completion counter (d_ws is poisoned by the harness)
    hipMemsetAsync(d_ws, 0, sizeof(unsigned), stream);
    vqc_kernel<<<NB, 256, 0, stream>>>(x, w, bias, gamma, beta,
                                       (unsigned*)d_ws, out);
}